// Round 6
// baseline (167.854 us; speedup 1.0000x reference)
//
#include <hip/hip_runtime.h>

// VectorQuantizer: B=16,T=8192,D=64,K=1024
// out = [quantized 131072x64 f32][indices 131072 as f32]
// Round 14: switch to 32x32x16 MFMA. Corrected pipe model: one 16x16x32
// MFMA occupies its SIMD ~19.4cy (4.85cy was per-CU!), so r8-r13 all sat
// at 3072 MFMA/SIMD x ~62cy wall/inst (19.4 pipe + ~40 overhead).
// 32x32x16 = 2x FLOP/inst (1536 inst/SIMD, 968 vs 844 FLOP/cy) + max TLP
// (32 tok/wave -> 4096 waves = 4/SIMD, <=128 VGPR). Per 32-code block:
// 12 MFMA as two interleaved chains (8-deep EE-init, 4-deep zero-init).
#define MTOK  131072
#define DIMD  64
#define KCODE 1024
#define TPB   128        // tokens per block = 4 waves x 32 tokens

typedef __bf16 bf16x8 __attribute__((ext_vector_type(8)));
typedef float  f32x4  __attribute__((ext_vector_type(4)));
typedef float  f32x16 __attribute__((ext_vector_type(16)));

__device__ __forceinline__ f32x16 mfma32(bf16x8 a, bf16x8 b, f32x16 c) {
    return __builtin_amdgcn_mfma_f32_32x32x16_bf16(a, b, c, 0, 0, 0);
}

// ---- prep: pack W into 32x32x16 A-fragment order + e2 tables ----
// wpk elt offset = cb32*4096 + term*2048 + ks*512 + lane*8 + j
// term: 0=hi, 1=lo residual. A-layout: row(code)=lane&31,
// k_global = ks*16 + (lane>>5)*8 + j.
__global__ __launch_bounds__(256) void prep_kernel(
    const float* __restrict__ w, __bf16* __restrict__ wpk,
    float* __restrict__ e2n, float* __restrict__ e2) {
    int b   = blockIdx.x;
    int tid = threadIdx.x;
    if (b < 64) {                       // pack blocks: b = cb32*2 + half
        int cb32 = b >> 1, half = b & 1;
        int idx  = half * 4 + (tid >> 6);   // 0..7 -> (term, ks)
        int term = idx >> 2, ks = idx & 3;
        int lane = tid & 63;
        int code = cb32 * 32 + (lane & 31);
        int k0   = ks * 16 + (lane >> 5) * 8;
        const float* src = w + (size_t)code * DIMD + k0;
        float4 v0 = *(const float4*)(src);
        float4 v1 = *(const float4*)(src + 4);
        float f[8] = {v0.x, v0.y, v0.z, v0.w, v1.x, v1.y, v1.z, v1.w};
        bf16x8 o;
#pragma unroll
        for (int j = 0; j < 8; ++j) {
            __bf16 h = (__bf16)f[j];
            o[j] = (term == 0) ? h : (__bf16)(f[j] - (float)h);
        }
        *(bf16x8*)(wpk + (size_t)cb32 * 4096 + term * 2048 + ks * 512 + lane * 8) = o;
    } else {                            // e2: one code/thread, exact r1 fma order
        int k2 = (b - 64) * 256 + tid;
        const float4* row = (const float4*)(w + (size_t)k2 * DIMD);
        float s = 0.f;
#pragma unroll
        for (int i = 0; i < 16; ++i) {
            float4 v = row[i];
            s = fmaf(v.x, v.x, s); s = fmaf(v.y, v.y, s);
            s = fmaf(v.z, v.z, s); s = fmaf(v.w, v.w, s);
        }
        e2[k2]  = s;
        e2n[k2] = -0.5f * s;
    }
}

__global__ __launch_bounds__(256, 4) void vq_main(
    const float* __restrict__ x, const float* __restrict__ wfull,
    const __bf16* __restrict__ wpk, const float* __restrict__ e2n_g,
    const float* __restrict__ e2_g, float* __restrict__ out) {

    const int tid  = threadIdx.x;
    const int blk  = blockIdx.x;
    const int lane = tid & 63;
    const int wv   = tid >> 6;          // wave -> tokens wv*32..+32
    const int col  = lane & 31;         // token within wave's tile
    const int hi   = lane >> 5;         // code-row half (C layout)
    const size_t tok0 = (size_t)blk * TPB + wv * 32;

    // ---- x B-fragments: col=token, k = ks*16 + hi*8 + j; hi/lo split ----
    bf16x8 XH[4], XL[4];
    {
        const float* xr = x + (tok0 + col) * DIMD;
#pragma unroll
        for (int ks = 0; ks < 4; ++ks) {
            float4 v0 = *(const float4*)(xr + ks * 16 + hi * 8);
            float4 v1 = *(const float4*)(xr + ks * 16 + hi * 8 + 4);
            float f[8] = {v0.x, v0.y, v0.z, v0.w, v1.x, v1.y, v1.z, v1.w};
            bf16x8 h8, l8;
#pragma unroll
            for (int j = 0; j < 8; ++j) {
                __bf16 hh = (__bf16)f[j];
                h8[j] = hh;
                l8[j] = (__bf16)(f[j] - (float)hh);
            }
            XH[ks] = h8;
            XL[ks] = l8;
        }
    }

    float b1 = -3e38f, b2 = -3e38f; int i1 = 0;

    const __bf16* wpl = wpk + (size_t)lane * 8;

    // preload cb32=0 W fragments
    bf16x8 WH[4], WL[4];
#pragma unroll
    for (int ks = 0; ks < 4; ++ks) {
        WH[ks] = *(const bf16x8*)(wpl + ks * 512);
        WL[ks] = *(const bf16x8*)(wpl + 2048 + ks * 512);
    }

    // C rows covered by reg r at this lane: row = rowoff[r] + 4*hi
    // (verified C/D layout: col=lane&31, row=(r&3)+8*(r>>2)+4*(lane>>5))
    for (int cb32 = 0; cb32 < 32; ++cb32) {
        // C-init = -e2/2 for this reg's code rows
        union { f32x16 v; f32x4 q[4]; } EE;
#pragma unroll
        for (int g = 0; g < 4; ++g)
            EE.q[g] = *(const f32x4*)(e2n_g + cb32 * 32 + hi * 4 + g * 8);

        f32x16 acc  = EE.v;        // chain 1: hihi + hilo (8 deep)
        f32x16 acc2 = {};          // chain 2: lohi (4 deep)
        __builtin_amdgcn_s_setprio(1);
        acc  = mfma32(WH[0], XH[0], acc);
        acc2 = mfma32(WL[0], XH[0], acc2);
        acc  = mfma32(WH[1], XH[1], acc);
        acc2 = mfma32(WL[1], XH[1], acc2);
        acc  = mfma32(WH[2], XH[2], acc);
        acc2 = mfma32(WL[2], XH[2], acc2);
        acc  = mfma32(WH[3], XH[3], acc);
        acc2 = mfma32(WL[3], XH[3], acc2);
        acc  = mfma32(WH[0], XL[0], acc);
        acc  = mfma32(WH[1], XL[1], acc);
        acc  = mfma32(WH[2], XL[2], acc);
        acc  = mfma32(WH[3], XL[3], acc);
        __builtin_amdgcn_s_setprio(0);

        if (cb32 + 1 < 32) {       // reload W for next block (after last use)
            const __bf16* wn = wpl + (size_t)(cb32 + 1) * 4096;
#pragma unroll
            for (int ks = 0; ks < 4; ++ks) {
                WL[ks] = *(const bf16x8*)(wn + 2048 + ks * 512);
                WH[ks] = *(const bf16x8*)(wn + ks * 512);
            }
        }

        // Tracker: top-1 (value+idx, strict > => ties keep lower code)
        // + top-2 value (med3). Codes ascend with r (rowoff ascending).
#pragma unroll
        for (int r = 0; r < 16; ++r) {
            const int rowoff = (r & 3) + 8 * (r >> 2);
            float a  = acc[r] + acc2[r];
            int iv   = cb32 * 32 + hi * 4 + rowoff;
            bool gt  = a > b1;
            i1 = gt ? iv : i1;
            b2 = __builtin_amdgcn_fmed3f(a, b1, b2);
            b1 = fmaxf(a, b1);
        }
    }

    // ---- merge: lane l and l^32 hold complementary code halves ----
    {
        float ob1 = __shfl_xor(b1, 32);
        float ob2 = __shfl_xor(b2, 32);
        int   oi  = __shfl_xor(i1, 32);
        bool take = (ob1 > b1) || (ob1 == b1 && oi < i1);
        b2 = fmaxf(fminf(ob1, b1), fmaxf(ob2, b2));
        i1 = take ? oi : i1;
        b1 = fmaxf(ob1, b1);
    }
    int myidx = i1;    // lane < 32 owns token tok0+lane (lane 32+ replicated)

    // ---- ballot-driven exact fp32 rescan of near-ties (round-1 numerics) ----
    {
        unsigned long long msk =
            __ballot((lane < 32) && (b1 - b2 < 2e-3f));
        while (msk) {
            int mm = __ffsll((unsigned long long)msk) - 1;
            msk &= msk - 1;
            int tloc = mm;                        // token within wave (0..31)
            const float4* xr = (const float4*)(x + (tok0 + tloc) * DIMD);
            float bv = 3e38f; int bi = 0;
            for (int j = 0; j < 16; ++j) {
                int k = lane * 16 + j;
                const float4* wr = (const float4*)(wfull + (size_t)k * DIMD);
                float s = 0.f;
#pragma unroll
                for (int i = 0; i < 16; ++i) {
                    float4 xv = xr[i], wv4 = wr[i];
                    s = fmaf(xv.x, wv4.x, s); s = fmaf(xv.y, wv4.y, s);
                    s = fmaf(xv.z, wv4.z, s); s = fmaf(xv.w, wv4.w, s);
                }
                float dv = fmaf(-2.f, s, e2_g[k]);
                if (dv < bv) { bv = dv; bi = k; }  // ties -> lower k
            }
#pragma unroll
            for (int mask2 = 1; mask2 <= 32; mask2 <<= 1) {
                float ov = __shfl_xor(bv, mask2);
                int   oi = __shfl_xor(bi, mask2);
                bool take = (ov < bv) || (ov == bv && oi < bi);
                bv = take ? ov : bv;
                bi = take ? oi : bi;
            }
            myidx = (lane == tloc) ? bi : myidx;
        }
    }

    // ---- outputs (nontemporal: pure streaming) ----
    if (lane < 32)
        __builtin_nontemporal_store((float)myidx,
                                    out + (size_t)MTOK * DIMD + tok0 + lane);

    // coalesced gather: per j, wave writes one contiguous 1KB segment;
    // codebook row read cooperatively (16 lanes per row, contiguous 256B)
    {
        float* obase = out + tok0 * DIMD;
#pragma unroll
        for (int j = 0; j < 8; ++j) {
            int srcl = j * 4 + (lane >> 4);        // token 0..31
            int gi   = __shfl(myidx, srcl);
            f32x4 v = *(const f32x4*)(wfull + (size_t)gi * DIMD + (lane & 15) * 4);
            __builtin_nontemporal_store(v, (f32x4*)(obase + j * 256 + lane * 4));
        }
    }
}

extern "C" void kernel_launch(void* const* d_in, const int* in_sizes, int n_in,
                              void* d_out, int out_size, void* d_ws, size_t ws_size,
                              hipStream_t stream) {
    const float* x = (const float*)d_in[0];
    const float* w = (const float*)d_in[1];
    float* out = (float*)d_out;

    // ws: [wpk 256K][e2n 4K][e2 4K]
    __bf16* wpk = (__bf16*)d_ws;
    float*  e2n = (float*)((char*)d_ws + 262144);
    float*  e2  = (float*)((char*)d_ws + 266240);

    prep_kernel<<<68, 256, 0, stream>>>(w, wpk, e2n, e2);
    vq_main<<<MTOK / TPB, 256, 0, stream>>>(x, w, wpk, e2n, e2, out);
}

// Round 7
// 152.078 us; speedup vs baseline: 1.1037x; 1.1037x over previous
//
#include <hip/hip_runtime.h>

// VectorQuantizer: B=16,T=8192,D=64,K=1024
// out = [quantized 131072x64 f32][indices 131072 as f32]
// Round 15: untested quadrant — W fully LDS-resident, NO steady-state
// barriers/VMEM, tracker software-pipelined one iteration back.
// Evidence: r8..r14 all sit at MfmaUtil ~26% (= pipe-time/wall with the
// calibrated 19.4cy/16x16-MFMA), wall 3-4x any pipe's demand, occupancy
// half nominal. Both prior structures kept a memory edge (vmcnt drain or
// L1/L2 latency) AND a tracker->MFMA serial dep in every iteration.
// Now: 1024-thr blocks (16 waves/CU), 128KB W staged per 512-code pass
// (2 barriers/pass), steady loop = [ds_read next][tracker prev][MFMA cur].
#define MTOK  131072
#define DIMD  64
#define KCODE 1024
#define TPB   512        // tokens per block = 16 waves x 32 tokens

typedef __bf16 bf16x8 __attribute__((ext_vector_type(8)));
typedef float  f32x4  __attribute__((ext_vector_type(4)));

__device__ __forceinline__ f32x4 mfma16(bf16x8 a, bf16x8 b, f32x4 c) {
    return __builtin_amdgcn_mfma_f32_16x16x32_bf16(a, b, c, 0, 0, 0);
}

// async global->LDS, 16B/lane; LDS dest = wave-uniform base + lane*16
__device__ __forceinline__ void g2l16(const void* g, void* l) {
    __builtin_amdgcn_global_load_lds(
        (const __attribute__((address_space(1))) unsigned int*)g,
        (__attribute__((address_space(3))) unsigned int*)l, 16, 0, 0);
}

// ---- prep: pack W into MFMA-fragment order + e2 tables (r5-verified) ----
// wpk element offset = cb*2048 + win*512 + lane*8
// win: 0=hi d0-31, 1=hi d32-63, 2=lo d0-31, 3=lo d32-63
// lane=(q,m): frag = w[cb*16+m][(win&1)*32+q*8 ..+8]
__global__ __launch_bounds__(256) void prep_kernel(
    const float* __restrict__ w, __bf16* __restrict__ wpk,
    float* __restrict__ e2n, float* __restrict__ e2) {
    int b   = blockIdx.x;
    int tid = threadIdx.x;
    if (b < 64) {                       // pack blocks
        int cb  = b;
        int win = tid >> 6, lane = tid & 63;
        int q = lane >> 4, m = lane & 15;
        int k = cb * 16 + m;
        int d0 = (win & 1) * 32 + q * 8;
        const float* src = w + (size_t)k * DIMD + d0;
        float4 v0 = *(const float4*)(src);
        float4 v1 = *(const float4*)(src + 4);
        float f[8] = {v0.x, v0.y, v0.z, v0.w, v1.x, v1.y, v1.z, v1.w};
        bf16x8 o;
#pragma unroll
        for (int j = 0; j < 8; ++j) {
            __bf16 h = (__bf16)f[j];
            o[j] = (win < 2) ? h : (__bf16)(f[j] - (float)h);
        }
        *(bf16x8*)(wpk + ((size_t)(cb * 4 + win) * 64 + lane) * 8) = o;
    } else {                            // e2: one code/thread, exact r1 fma order
        int k2 = (b - 64) * 256 + tid;
        const float4* row = (const float4*)(w + (size_t)k2 * DIMD);
        float s = 0.f;
#pragma unroll
        for (int i = 0; i < 16; ++i) {
            float4 v = row[i];
            s = fmaf(v.x, v.x, s); s = fmaf(v.y, v.y, s);
            s = fmaf(v.z, v.z, s); s = fmaf(v.w, v.w, s);
        }
        e2[k2]  = s;
        e2n[k2] = -0.5f * s;
    }
}

__global__ __launch_bounds__(1024, 4) void vq_main(
    const float* __restrict__ x, const float* __restrict__ wfull,
    const __bf16* __restrict__ wpk, const float* __restrict__ e2n_g,
    const float* __restrict__ e2_g, float* __restrict__ out) {

    // 128KB W (32 x 16-code blocks x 4KB) + 4KB e2n = 132KB -> 1 block/CU
    __shared__ __align__(16) __bf16 ldsW[65536];
    __shared__ __align__(16) float  ldsE[KCODE];

    const int tid  = threadIdx.x;
    const int blk  = blockIdx.x;
    const int lane = tid & 63;
    const int wv   = tid >> 6;      // wave 0..15 -> tokens wv*32..+32
    const int q    = lane >> 4;
    const int m    = lane & 15;
    const size_t tok0 = (size_t)blk * TPB + wv * 32;   // wave's first token

    // ---- stage pass-0 W half (128KB) + full e2n table (4KB) ----
    {
        const char* gw = (const char*)wpk;
        char* lw = (char*)ldsW;
#pragma unroll
        for (int j = 0; j < 8; ++j)
            g2l16(gw + j * 16384 + tid * 16, lw + j * 16384 + tid * 16);
        if (tid < 256)   // waves 0..3, full waves
            g2l16((const char*)e2n_g + tid * 16, (char*)ldsE + tid * 16);
    }

    // ---- x fragments straight from global, hi/lo split in registers ----
    bf16x8 bx[2][4];
#pragma unroll
    for (int tg = 0; tg < 2; ++tg) {
        const float* xr = x + (tok0 + tg * 16 + m) * DIMD;
#pragma unroll
        for (int h = 0; h < 2; ++h) {
            float4 v0 = *(const float4*)(xr + h * 32 + q * 8);
            float4 v1 = *(const float4*)(xr + h * 32 + q * 8 + 4);
            float f[8] = {v0.x, v0.y, v0.z, v0.w, v1.x, v1.y, v1.z, v1.w};
            bf16x8 hi, lo;
#pragma unroll
            for (int j = 0; j < 8; ++j) {
                __bf16 hh = (__bf16)f[j];
                hi[j] = hh;
                lo[j] = (__bf16)(f[j] - (float)hh);
            }
            bx[tg][h]     = hi;
            bx[tg][2 + h] = lo;
        }
    }

    float b1[2], b2[2]; int i1[2];
#pragma unroll
    for (int tg = 0; tg < 2; ++tg) { b1[tg] = -3e38f; b2[tg] = -3e38f; i1[tg] = 0; }

    // r9-verified chain order: 2 token groups, 6-deep each, interleaved.
    auto chains = [&](const bf16x8& A0, const bf16x8& A1, const bf16x8& A2,
                      const bf16x8& A3, const f32x4& EE, f32x4& t0, f32x4& t1) {
        __builtin_amdgcn_s_setprio(1);
        t0 = mfma16(A0, bx[0][0], EE);   // w_hi*x_hi d0-31
        t1 = mfma16(A0, bx[1][0], EE);
        t0 = mfma16(A1, bx[0][1], t0);   // w_hi*x_hi d32-63
        t1 = mfma16(A1, bx[1][1], t1);
        t0 = mfma16(A0, bx[0][2], t0);   // w_hi*x_lo
        t1 = mfma16(A0, bx[1][2], t1);
        t0 = mfma16(A1, bx[0][3], t0);
        t1 = mfma16(A1, bx[1][3], t1);
        t0 = mfma16(A2, bx[0][0], t0);   // w_lo*x_hi
        t1 = mfma16(A2, bx[1][0], t1);
        t0 = mfma16(A3, bx[0][1], t0);
        t1 = mfma16(A3, bx[1][1], t1);
        __builtin_amdgcn_s_setprio(0);
    };

    // Tracker: top-1 (value+idx, strict > => ties keep lower code)
    // + top-2 value (med3). Same per-eval op order as verified r5 numerics.
    auto tracker = [&](const f32x4& t0, const f32x4& t1, int cbase) {
#pragma unroll
        for (int r = 0; r < 4; ++r) {
            float a  = t0[r];
            int iv   = cbase + q * 4 + r;
            bool gt  = a > b1[0];
            i1[0] = gt ? iv : i1[0];
            b2[0] = __builtin_amdgcn_fmed3f(a, b1[0], b2[0]);
            b1[0] = fmaxf(a, b1[0]);
        }
#pragma unroll
        for (int r = 0; r < 4; ++r) {
            float a  = t1[r];
            int iv   = cbase + q * 4 + r;
            bool gt  = a > b1[1];
            i1[1] = gt ? iv : i1[1];
            b2[1] = __builtin_amdgcn_fmed3f(a, b1[1], b2[1]);
            b1[1] = fmaxf(a, b1[1]);
        }
    };

    __syncthreads();   // pass-0 W + e2n resident (barrier drains vmcnt)

    // ---- 2 passes x 32 16-code blocks; steady state has NO barriers,
    //      NO VMEM: [ds_read next W][tracker prev acc][MFMA cur] ----
    for (int pass = 0; pass < 2; ++pass) {
        if (pass) {
            __syncthreads();   // all waves done reading pass-0 LDS
            const char* gw = (const char*)wpk + 131072;
            char* lw = (char*)ldsW;
#pragma unroll
            for (int j = 0; j < 8; ++j)
                g2l16(gw + j * 16384 + tid * 16, lw + j * 16384 + tid * 16);
            __syncthreads();   // pass-1 W resident
        }

        const __bf16* wb = ldsW + lane * 8;   // frag base; rest is imm offs
        const int eb  = pass * 512 + q * 4;   // ldsE float index base
        const int cb0 = pass * 32;            // global 16-code block base

        bf16x8 Wa0, Wa1, Wa2, Wa3, Wb0, Wb1, Wb2, Wb3;
        f32x4  Ea, Eb, tA0, tA1, tB0, tB1;

        // step 0: load + compute cb=0 -> acc A (no tracker yet)
        Wa0 = *(const bf16x8*)(wb + 0);
        Wa1 = *(const bf16x8*)(wb + 512);
        Wa2 = *(const bf16x8*)(wb + 1024);
        Wa3 = *(const bf16x8*)(wb + 1536);
        Ea  = *(const f32x4*)&ldsE[eb];
        chains(Wa0, Wa1, Wa2, Wa3, Ea, tA0, tA1);

        for (int cb = 1; cb <= 29; cb += 2) {
            {   // load set B = cb; tracker(A=cb-1); MFMA B
                const __bf16* wc = wb + cb * 2048;
                Wb0 = *(const bf16x8*)(wc + 0);
                Wb1 = *(const bf16x8*)(wc + 512);
                Wb2 = *(const bf16x8*)(wc + 1024);
                Wb3 = *(const bf16x8*)(wc + 1536);
                Eb  = *(const f32x4*)&ldsE[eb + cb * 16];
                tracker(tA0, tA1, (cb0 + cb - 1) * 16);
                chains(Wb0, Wb1, Wb2, Wb3, Eb, tB0, tB1);
            }
            {   // load set A = cb+1; tracker(B=cb); MFMA A
                const __bf16* wc = wb + (cb + 1) * 2048;
                Wa0 = *(const bf16x8*)(wc + 0);
                Wa1 = *(const bf16x8*)(wc + 512);
                Wa2 = *(const bf16x8*)(wc + 1024);
                Wa3 = *(const bf16x8*)(wc + 1536);
                Ea  = *(const f32x4*)&ldsE[eb + (cb + 1) * 16];
                tracker(tB0, tB1, (cb0 + cb) * 16);
                chains(Wa0, Wa1, Wa2, Wa3, Ea, tA0, tA1);
            }
        }
        // tail: cb=31 into B; tracker 30 (in A), then 31
        {
            const __bf16* wc = wb + 31 * 2048;
            Wb0 = *(const bf16x8*)(wc + 0);
            Wb1 = *(const bf16x8*)(wc + 512);
            Wb2 = *(const bf16x8*)(wc + 1024);
            Wb3 = *(const bf16x8*)(wc + 1536);
            Eb  = *(const f32x4*)&ldsE[eb + 31 * 16];
            tracker(tA0, tA1, (cb0 + 30) * 16);
            chains(Wb0, Wb1, Wb2, Wb3, Eb, tB0, tB1);
            tracker(tB0, tB1, (cb0 + 31) * 16);
        }
    }

    // ---- cross-quad merge: lanes m,m+16,m+32,m+48 hold disjoint code sets ----
    float B1f[2], B2f[2]; int I1f[2];
#pragma unroll
    for (int tg = 0; tg < 2; ++tg) {
        float B1 = b1[tg], B2 = b2[tg]; int I1 = i1[tg];
#pragma unroll
        for (int mask = 16; mask <= 32; mask <<= 1) {
            float ob1 = __shfl_xor(B1, mask);
            float ob2 = __shfl_xor(B2, mask);
            int   oi  = __shfl_xor(I1, mask);
            bool take = (ob1 > B1) || (ob1 == B1 && oi < I1);
            B2 = fmaxf(fminf(ob1, B1), fmaxf(ob2, B2));
            I1 = take ? oi : I1;
            B1 = fmaxf(ob1, B1);
        }
        B1f[tg] = B1; B2f[tg] = B2; I1f[tg] = I1;   // replicated across quads
    }

    // token t (0..31) of this wave -> its index; lanes 0..31 own token lane
    int myidx;
    {
        int src = lane & 15;
        int v0 = __shfl(I1f[0], src);
        int v1 = __shfl(I1f[1], src);
        myidx = ((lane >> 4) & 1) ? v1 : v0;
    }

    // ---- ballot-driven exact fp32 rescan of near-ties (round-1 numerics) ----
#pragma unroll
    for (int tg = 0; tg < 2; ++tg) {
        unsigned long long msk =
            __ballot((lane < 16) && (B1f[tg] - B2f[tg] < 2e-3f));
        while (msk) {
            int mm = __ffsll((unsigned long long)msk) - 1;
            msk &= msk - 1;
            int tloc = tg * 16 + mm;              // token within this wave (0..31)
            const float4* xr = (const float4*)(x + (tok0 + tloc) * DIMD);
            float bv = 3e38f; int bi = 0;
            for (int j = 0; j < 16; ++j) {
                int k = lane * 16 + j;
                const float4* wr = (const float4*)(wfull + (size_t)k * DIMD);
                float s = 0.f;
#pragma unroll
                for (int i = 0; i < 16; ++i) {
                    float4 xv = xr[i], wv4 = wr[i];
                    s = fmaf(xv.x, wv4.x, s); s = fmaf(xv.y, wv4.y, s);
                    s = fmaf(xv.z, wv4.z, s); s = fmaf(xv.w, wv4.w, s);
                }
                float dv = fmaf(-2.f, s, e2_g[k]);
                if (dv < bv) { bv = dv; bi = k; }  // ties -> lower k
            }
#pragma unroll
            for (int mask2 = 1; mask2 <= 32; mask2 <<= 1) {
                float ov = __shfl_xor(bv, mask2);
                int   oi = __shfl_xor(bi, mask2);
                bool take = (ov < bv) || (ov == bv && oi < bi);
                bv = take ? ov : bv;
                bi = take ? oi : bi;
            }
            myidx = (lane == tloc) ? bi : myidx;
        }
    }

    // ---- outputs (nontemporal: pure streaming) ----
    if (lane < 32)
        __builtin_nontemporal_store((float)myidx,
                                    out + (size_t)MTOK * DIMD + tok0 + lane);

    // coalesced gather: per j, wave writes one contiguous 1KB segment;
    // codebook row read cooperatively (16 lanes per row, contiguous 256B)
    {
        float* obase = out + tok0 * DIMD;
#pragma unroll
        for (int j = 0; j < 8; ++j) {
            int srcl = j * 4 + (lane >> 4);        // token 0..31
            int gi   = __shfl(myidx, srcl);
            f32x4 v = *(const f32x4*)(wfull + (size_t)gi * DIMD + (lane & 15) * 4);
            __builtin_nontemporal_store(v, (f32x4*)(obase + j * 256 + lane * 4));
        }
    }
}

extern "C" void kernel_launch(void* const* d_in, const int* in_sizes, int n_in,
                              void* d_out, int out_size, void* d_ws, size_t ws_size,
                              hipStream_t stream) {
    const float* x = (const float*)d_in[0];
    const float* w = (const float*)d_in[1];
    float* out = (float*)d_out;

    // ws: [wpk 256K][e2n 4K][e2 4K]
    __bf16* wpk = (__bf16*)d_ws;
    float*  e2n = (float*)((char*)d_ws + 262144);
    float*  e2  = (float*)((char*)d_ws + 266240);

    prep_kernel<<<68, 256, 0, stream>>>(w, wpk, e2n, e2);
    vq_main<<<MTOK / TPB, 1024, 0, stream>>>(x, w, wpk, e2n, e2, out);
}

// Round 8
// 147.717 us; speedup vs baseline: 1.1363x; 1.0295x over previous
//
#include <hip/hip_runtime.h>

// VectorQuantizer: B=16,T=8192,D=64,K=1024
// out = [quantized 131072x64 f32][indices 131072 as f32]
// Round 16: r15 was LDS-read-BW-bound (18.9MB/CU over 88us = 214 GB/s/CU
// >= the 204 GB/s/CU ds_read_b128 ceiling; conflicts 0). W-stream LDS cost
// is per-wave-fixed, so: 64 tokens/wave halves LDS demand/CU and gives 4
// independent 6-deep MFMA chains (r13's ILP, fed from LDS so the compiler
// can't sink staging). 512-thr blocks (8 waves), grid=256 = 1 block/CU,
// W in 4x64KB double-buffered chunks (4 barriers total), tracker pipelined
// one cb back (r15 pattern). MFMA floor: 3072 inst/SIMD x 19.4cy ~ 25us.
#define MTOK  131072
#define DIMD  64
#define KCODE 1024
#define TPB   512        // tokens per block = 8 waves x 64 tokens

typedef __bf16 bf16x8 __attribute__((ext_vector_type(8)));
typedef float  f32x4  __attribute__((ext_vector_type(4)));

__device__ __forceinline__ f32x4 mfma16(bf16x8 a, bf16x8 b, f32x4 c) {
    return __builtin_amdgcn_mfma_f32_16x16x32_bf16(a, b, c, 0, 0, 0);
}

// async global->LDS, 16B/lane; LDS dest = wave-uniform base + lane*16
__device__ __forceinline__ void g2l16(const void* g, void* l) {
    __builtin_amdgcn_global_load_lds(
        (const __attribute__((address_space(1))) unsigned int*)g,
        (__attribute__((address_space(3))) unsigned int*)l, 16, 0, 0);
}

// ---- prep: pack W into MFMA-fragment order + e2 tables (r5-verified) ----
// wpk element offset = cb*2048 + win*512 + lane*8
// win: 0=hi d0-31, 1=hi d32-63, 2=lo d0-31, 3=lo d32-63
// lane=(q,m): frag = w[cb*16+m][(win&1)*32+q*8 ..+8]
__global__ __launch_bounds__(256) void prep_kernel(
    const float* __restrict__ w, __bf16* __restrict__ wpk,
    float* __restrict__ e2n, float* __restrict__ e2) {
    int b   = blockIdx.x;
    int tid = threadIdx.x;
    if (b < 64) {                       // pack blocks
        int cb  = b;
        int win = tid >> 6, lane = tid & 63;
        int q = lane >> 4, m = lane & 15;
        int k = cb * 16 + m;
        int d0 = (win & 1) * 32 + q * 8;
        const float* src = w + (size_t)k * DIMD + d0;
        float4 v0 = *(const float4*)(src);
        float4 v1 = *(const float4*)(src + 4);
        float f[8] = {v0.x, v0.y, v0.z, v0.w, v1.x, v1.y, v1.z, v1.w};
        bf16x8 o;
#pragma unroll
        for (int j = 0; j < 8; ++j) {
            __bf16 h = (__bf16)f[j];
            o[j] = (win < 2) ? h : (__bf16)(f[j] - (float)h);
        }
        *(bf16x8*)(wpk + ((size_t)(cb * 4 + win) * 64 + lane) * 8) = o;
    } else {                            // e2: one code/thread, exact r1 fma order
        int k2 = (b - 64) * 256 + tid;
        const float4* row = (const float4*)(w + (size_t)k2 * DIMD);
        float s = 0.f;
#pragma unroll
        for (int i = 0; i < 16; ++i) {
            float4 v = row[i];
            s = fmaf(v.x, v.x, s); s = fmaf(v.y, v.y, s);
            s = fmaf(v.z, v.z, s); s = fmaf(v.w, v.w, s);
        }
        e2[k2]  = s;
        e2n[k2] = -0.5f * s;
    }
}

// LOADW: pull 16-code block l's fragments from LDS buffer into a named set
#define LOADW(S, WB, L)                                        \
    W##S##0 = *(const bf16x8*)((WB) + (L) * 2048 + 0);         \
    W##S##1 = *(const bf16x8*)((WB) + (L) * 2048 + 512);       \
    W##S##2 = *(const bf16x8*)((WB) + (L) * 2048 + 1024);      \
    W##S##3 = *(const bf16x8*)((WB) + (L) * 2048 + 1536);      \
    E##S    = *(const f32x4*)&ldsE[(CB0 + (L)) * 16 + q * 4];

// CHAINS: 4 independent 6-deep chains (one per token group), round-robin
// by depth. Per-tg op order identical to r9/r13-verified numerics.
#define CHAINS(S)                                              \
    __builtin_amdgcn_s_setprio(1);                             \
    t##S##0 = mfma16(W##S##0, bx[0][0], E##S);                 \
    t##S##1 = mfma16(W##S##0, bx[1][0], E##S);                 \
    t##S##2 = mfma16(W##S##0, bx[2][0], E##S);                 \
    t##S##3 = mfma16(W##S##0, bx[3][0], E##S);                 \
    t##S##0 = mfma16(W##S##1, bx[0][1], t##S##0);              \
    t##S##1 = mfma16(W##S##1, bx[1][1], t##S##1);              \
    t##S##2 = mfma16(W##S##1, bx[2][1], t##S##2);              \
    t##S##3 = mfma16(W##S##1, bx[3][1], t##S##3);              \
    t##S##0 = mfma16(W##S##0, bx[0][2], t##S##0);              \
    t##S##1 = mfma16(W##S##0, bx[1][2], t##S##1);              \
    t##S##2 = mfma16(W##S##0, bx[2][2], t##S##2);              \
    t##S##3 = mfma16(W##S##0, bx[3][2], t##S##3);              \
    t##S##0 = mfma16(W##S##1, bx[0][3], t##S##0);              \
    t##S##1 = mfma16(W##S##1, bx[1][3], t##S##1);              \
    t##S##2 = mfma16(W##S##1, bx[2][3], t##S##2);              \
    t##S##3 = mfma16(W##S##1, bx[3][3], t##S##3);              \
    t##S##0 = mfma16(W##S##2, bx[0][0], t##S##0);              \
    t##S##1 = mfma16(W##S##2, bx[1][0], t##S##1);              \
    t##S##2 = mfma16(W##S##2, bx[2][0], t##S##2);              \
    t##S##3 = mfma16(W##S##2, bx[3][0], t##S##3);              \
    t##S##0 = mfma16(W##S##3, bx[0][1], t##S##0);              \
    t##S##1 = mfma16(W##S##3, bx[1][1], t##S##1);              \
    t##S##2 = mfma16(W##S##3, bx[2][1], t##S##2);              \
    t##S##3 = mfma16(W##S##3, bx[3][1], t##S##3);              \
    __builtin_amdgcn_s_setprio(0);

// TRACK: top-1 (value+idx, strict > => ties keep lower code) + top-2
// value (med3). Eval order: tg ascending, r ascending (r5-verified).
#define TRACK(S, CBASE)                                        \
    {                                                          \
        f32x4 tt_[4] = {t##S##0, t##S##1, t##S##2, t##S##3};   \
        _Pragma("unroll")                                      \
        for (int tg_ = 0; tg_ < 4; ++tg_) {                    \
            _Pragma("unroll")                                  \
            for (int r_ = 0; r_ < 4; ++r_) {                   \
                float a_ = tt_[tg_][r_];                       \
                int iv_  = (CBASE) + q * 4 + r_;               \
                bool gt_ = a_ > b1[tg_];                       \
                i1[tg_] = gt_ ? iv_ : i1[tg_];                 \
                b2[tg_] = __builtin_amdgcn_fmed3f(a_, b1[tg_], b2[tg_]); \
                b1[tg_] = fmaxf(a_, b1[tg_]);                  \
            }                                                  \
        }                                                      \
    }

__global__ __launch_bounds__(512, 2) void vq_main(
    const float* __restrict__ x, const float* __restrict__ wfull,
    const __bf16* __restrict__ wpk, const float* __restrict__ e2n_g,
    const float* __restrict__ e2_g, float* __restrict__ out) {

    // 2 x 64KB W chunk double-buffer + 4KB e2n = 132KB -> 1 block/CU
    __shared__ __align__(16) __bf16 ldsW[2][32768];
    __shared__ __align__(16) float  ldsE[KCODE];

    const int tid  = threadIdx.x;
    const int blk  = blockIdx.x;
    const int lane = tid & 63;
    const int wv   = tid >> 6;      // wave 0..7 -> tokens wv*64..+64
    const int q    = lane >> 4;
    const int m    = lane & 15;
    const size_t tok0 = (size_t)blk * TPB + wv * 64;   // wave's first token

    // ---- stage chunk 0 (64KB) + full e2n table (4KB) ----
    {
        const char* gw = (const char*)wpk + tid * 16;
        char* lw = (char*)&ldsW[0][0] + tid * 16;
#pragma unroll
        for (int j = 0; j < 8; ++j)
            g2l16(gw + j * 8192, lw + j * 8192);
        if (tid < 256)
            g2l16((const char*)e2n_g + tid * 16, (char*)ldsE + tid * 16);
    }

    // ---- x fragments straight from global, hi/lo split in registers ----
    // 4 token groups of 16: token t = tg*16 + m
    bf16x8 bx[4][4];
#pragma unroll
    for (int tg = 0; tg < 4; ++tg) {
        const float* xr = x + (tok0 + tg * 16 + m) * DIMD;
#pragma unroll
        for (int h = 0; h < 2; ++h) {
            float4 v0 = *(const float4*)(xr + h * 32 + q * 8);
            float4 v1 = *(const float4*)(xr + h * 32 + q * 8 + 4);
            float f[8] = {v0.x, v0.y, v0.z, v0.w, v1.x, v1.y, v1.z, v1.w};
            bf16x8 hi, lo;
#pragma unroll
            for (int j = 0; j < 8; ++j) {
                __bf16 hh = (__bf16)f[j];
                hi[j] = hh;
                lo[j] = (__bf16)(f[j] - (float)hh);
            }
            bx[tg][h]     = hi;
            bx[tg][2 + h] = lo;
        }
    }

    float b1[4], b2[4]; int i1[4];
#pragma unroll
    for (int tg = 0; tg < 4; ++tg) { b1[tg] = -3e38f; b2[tg] = -3e38f; i1[tg] = 0; }

    __syncthreads();   // chunk 0 + e2n resident (barrier drains vmcnt)

    // ---- 4 chunks x 16 cbs; stage next chunk under current compute;
    //      steady state: [ds_read next cb][tracker prev acc][MFMA cur] ----
    for (int ch = 0; ch < 4; ++ch) {
        if (ch + 1 < 4) {   // async prefetch next 64KB chunk (other buffer)
            const char* gw = (const char*)wpk + (size_t)(ch + 1) * 65536 + tid * 16;
            char* lw = (char*)&ldsW[(ch + 1) & 1][0] + tid * 16;
#pragma unroll
            for (int j = 0; j < 8; ++j)
                g2l16(gw + j * 8192, lw + j * 8192);
        }

        const __bf16* wb = &ldsW[ch & 1][0] + lane * 8;  // frag base
        const int CB0 = ch * 16;                          // global cb base

        bf16x8 WA0, WA1, WA2, WA3, WB0, WB1, WB2, WB3;
        f32x4  EA, EB, tA0, tA1, tA2, tA3, tB0, tB1, tB2, tB3;

        // step 0: load + compute cb-local 0 -> set A (no tracker yet)
        LOADW(A, wb, 0);
        CHAINS(A);

        for (int l = 1; l <= 13; l += 2) {
            // load set B = l; tracker(A = l-1); MFMA B
            LOADW(B, wb, l);
            TRACK(A, (CB0 + l - 1) * 16);
            CHAINS(B);
            // load set A = l+1; tracker(B = l); MFMA A
            LOADW(A, wb, l + 1);
            TRACK(B, (CB0 + l) * 16);
            CHAINS(A);
        }
        // tail: l=15 into B; tracker 14 (in A); MFMA B; tracker 15
        LOADW(B, wb, 15);
        TRACK(A, (CB0 + 14) * 16);
        CHAINS(B);
        TRACK(B, (CB0 + 15) * 16);

        if (ch + 1 < 4)
            __syncthreads();   // all waves done with buf ch&1; prefetch landed
    }

    // ---- cross-quad merge: lanes m,m+16,m+32,m+48 hold disjoint code sets ----
    float B1f[4], B2f[4]; int I1f[4];
#pragma unroll
    for (int tg = 0; tg < 4; ++tg) {
        float B1 = b1[tg], B2 = b2[tg]; int I1 = i1[tg];
#pragma unroll
        for (int mask = 16; mask <= 32; mask <<= 1) {
            float ob1 = __shfl_xor(B1, mask);
            float ob2 = __shfl_xor(B2, mask);
            int   oi  = __shfl_xor(I1, mask);
            bool take = (ob1 > B1) || (ob1 == B1 && oi < I1);
            B2 = fmaxf(fminf(ob1, B1), fmaxf(ob2, B2));
            I1 = take ? oi : I1;
            B1 = fmaxf(ob1, B1);
        }
        B1f[tg] = B1; B2f[tg] = B2; I1f[tg] = I1;   // replicated across quads
    }

    // token t (0..63) of this wave -> its index; lane owns token `lane`
    int myidx;
    {
        int src = lane & 15;
        int v0 = __shfl(I1f[0], src);
        int v1 = __shfl(I1f[1], src);
        int v2 = __shfl(I1f[2], src);
        int v3 = __shfl(I1f[3], src);
        int hi2 = lane >> 4;            // which token group
        int va = (hi2 & 1) ? v1 : v0;
        int vb = (hi2 & 1) ? v3 : v2;
        myidx = (hi2 & 2) ? vb : va;
    }

    // ---- ballot-driven exact fp32 rescan of near-ties (round-1 numerics) ----
#pragma unroll
    for (int tg = 0; tg < 4; ++tg) {
        unsigned long long msk =
            __ballot((lane < 16) && (B1f[tg] - B2f[tg] < 2e-3f));
        while (msk) {
            int mm = __ffsll((unsigned long long)msk) - 1;
            msk &= msk - 1;
            int tloc = tg * 16 + mm;              // token within this wave (0..63)
            const float4* xr = (const float4*)(x + (tok0 + tloc) * DIMD);
            float bv = 3e38f; int bi = 0;
            for (int j = 0; j < 16; ++j) {
                int k = lane * 16 + j;
                const float4* wr = (const float4*)(wfull + (size_t)k * DIMD);
                float s = 0.f;
#pragma unroll
                for (int i = 0; i < 16; ++i) {
                    float4 xv = xr[i], wv4 = wr[i];
                    s = fmaf(xv.x, wv4.x, s); s = fmaf(xv.y, wv4.y, s);
                    s = fmaf(xv.z, wv4.z, s); s = fmaf(xv.w, wv4.w, s);
                }
                float dv = fmaf(-2.f, s, e2_g[k]);
                if (dv < bv) { bv = dv; bi = k; }  // ties -> lower k
            }
#pragma unroll
            for (int mask2 = 1; mask2 <= 32; mask2 <<= 1) {
                float ov = __shfl_xor(bv, mask2);
                int   oi = __shfl_xor(bi, mask2);
                bool take = (ov < bv) || (ov == bv && oi < bi);
                bv = take ? ov : bv;
                bi = take ? oi : bi;
            }
            myidx = (lane == tloc) ? bi : myidx;
        }
    }

    // ---- outputs (nontemporal: pure streaming) ----
    __builtin_nontemporal_store((float)myidx,
                                out + (size_t)MTOK * DIMD + tok0 + lane);

    // coalesced gather: per j, wave writes one contiguous 1KB segment;
    // codebook row read cooperatively (16 lanes per row, contiguous 256B)
    {
        float* obase = out + tok0 * DIMD;
#pragma unroll
        for (int j = 0; j < 16; ++j) {
            int srcl = j * 4 + (lane >> 4);        // token 0..63
            int gi   = __shfl(myidx, srcl);
            f32x4 v = *(const f32x4*)(wfull + (size_t)gi * DIMD + (lane & 15) * 4);
            __builtin_nontemporal_store(v, (f32x4*)(obase + j * 256 + lane * 4));
        }
    }
}

extern "C" void kernel_launch(void* const* d_in, const int* in_sizes, int n_in,
                              void* d_out, int out_size, void* d_ws, size_t ws_size,
                              hipStream_t stream) {
    const float* x = (const float*)d_in[0];
    const float* w = (const float*)d_in[1];
    float* out = (float*)d_out;

    // ws: [wpk 256K][e2n 4K][e2 4K]
    __bf16* wpk = (__bf16*)d_ws;
    float*  e2n = (float*)((char*)d_ws + 262144);
    float*  e2  = (float*)((char*)d_ws + 266240);

    prep_kernel<<<68, 256, 0, stream>>>(w, wpk, e2n, e2);
    vq_main<<<MTOK / TPB, 512, 0, stream>>>(x, w, wpk, e2n, e2, out);
}